// Round 1
// baseline (4593.394 us; speedup 1.0000x reference)
//
#include <hip/hip_runtime.h>
#include <cstddef>

// ---------------------------------------------------------------------------
// Model: embed+concat -> Linear(80->96) -> 3x SAGEConv(96, mean) -> MLP(96->256->256->1)
// All fp32. N = #nodes (in_sizes[1]), E = #edges (in_sizes[2]/2).
// ---------------------------------------------------------------------------

#define NB 256  // threads per block for all kernels

// ---- degree count ----------------------------------------------------------
__global__ __launch_bounds__(NB) void count_kernel(const int* __restrict__ dst,
                                                   float* __restrict__ cnt, int E) {
    int e = blockIdx.x * NB + threadIdx.x;
    if (e < E) atomicAdd(&cnt[dst[e]], 1.0f);
}

__global__ __launch_bounds__(NB) void invcnt_kernel(float* __restrict__ cnt, int n) {
    int i = blockIdx.x * NB + threadIdx.x;
    if (i < n) cnt[i] = 1.0f / fmaxf(cnt[i], 1.0f);
}

// ---- embedding + concat + Linear(80->96) ----------------------------------
__global__ __launch_bounds__(NB) void embed_lin_kernel(
    const int* __restrict__ xl, const int* __restrict__ xr,
    const float* __restrict__ lemb, const float* __restrict__ remb,
    const float* __restrict__ W /*96x80*/, const float* __restrict__ b,
    float* __restrict__ Y, int nrows) {
    constexpr int K = 80, OUT = 96, BM = 32;
    __shared__ float Fs[BM][K];
    const int t = threadIdx.x;
    const int rowBase = blockIdx.x * BM;

    for (int i = t; i < BM * K; i += NB) {
        int n = i / K, j = i - n * K;
        int r = rowBase + n;
        float v = 0.f;
        if (r < nrows) {
            if (j < 64) {
                int l = j >> 4, c = j & 15;
                v = lemb[(size_t)xl[r * 4 + l] * 16 + c];
            } else {
                v = remb[(size_t)xr[r] * 16 + (j - 64)];
            }
        }
        Fs[n][j] = v;
    }
    __syncthreads();

    for (int i = t; i < BM * OUT; i += NB) {
        int n = i / OUT, o = i - n * OUT;
        int r = rowBase + n;
        if (r >= nrows) continue;
        float acc = b[o];
        #pragma unroll
        for (int k = 0; k < K; k += 4) {
            float4 xv = *reinterpret_cast<const float4*>(&Fs[n][k]);
            float4 wv = *reinterpret_cast<const float4*>(&W[(size_t)o * K + k]);
            acc += xv.x * wv.x + xv.y * wv.y + xv.z * wv.z + xv.w * wv.w;
        }
        Y[(size_t)r * OUT + o] = acc;
    }
}

// ---- scatter-add of messages (per edge,channel) ----------------------------
__global__ __launch_bounds__(NB) void scatter_add_kernel(
    const float* __restrict__ X, const int* __restrict__ src,
    const int* __restrict__ dst, float* __restrict__ G, int total) {
    int i = blockIdx.x * NB + threadIdx.x;
    if (i >= total) return;
    int e = i / 96;
    int c = i - e * 96;
    atomicAdd(&G[(size_t)dst[e] * 96 + c], X[(size_t)src[e] * 96 + c]);
}

// ---- fused SAGE: Y = relu( (G*invc) @ Wl^T + bl + X @ Wr^T ) ---------------
template <int K, int OUT, int BM>
__global__ __launch_bounds__(NB) void sage_gemm_kernel(
    const float* __restrict__ X, const float* __restrict__ G,
    const float* __restrict__ invc,
    const float* __restrict__ Wl, const float* __restrict__ bl,
    const float* __restrict__ Wr, float* __restrict__ Y, int nrows) {
    __shared__ float Xs[BM][K];
    __shared__ float Gs[BM][K];
    const int t = threadIdx.x;
    const int rowBase = blockIdx.x * BM;

    for (int i = t; i < BM * K; i += NB) {
        int n = i / K, k = i - n * K;
        int r = rowBase + n;
        if (r < nrows) {
            float ic = invc[r];
            Xs[n][k] = X[(size_t)r * K + k];
            Gs[n][k] = G[(size_t)r * K + k] * ic;
        } else {
            Xs[n][k] = 0.f;
            Gs[n][k] = 0.f;
        }
    }
    __syncthreads();

    for (int i = t; i < BM * OUT; i += NB) {
        int n = i / OUT, o = i - n * OUT;
        int r = rowBase + n;
        if (r >= nrows) continue;
        float acc = bl[o];
        #pragma unroll
        for (int k = 0; k < K; k += 4) {
            float4 gv = *reinterpret_cast<const float4*>(&Gs[n][k]);
            float4 lv = *reinterpret_cast<const float4*>(&Wl[(size_t)o * K + k]);
            float4 xv = *reinterpret_cast<const float4*>(&Xs[n][k]);
            float4 rv = *reinterpret_cast<const float4*>(&Wr[(size_t)o * K + k]);
            acc += gv.x * lv.x + gv.y * lv.y + gv.z * lv.z + gv.w * lv.w;
            acc += xv.x * rv.x + xv.y * rv.y + xv.z * rv.z + xv.w * rv.w;
        }
        acc = fmaxf(acc, 0.f);
        Y[(size_t)r * OUT + o] = acc;
    }
}

// ---- generic GEMM + bias (+relu): Y[n][OUT] = act(X[n][K] @ W^T + b) -------
template <int K, int OUT, int BM, bool RELU>
__global__ __launch_bounds__(NB) void gemm_bias_kernel(
    const float* __restrict__ X, const float* __restrict__ W,
    const float* __restrict__ b, float* __restrict__ Y, int nrows) {
    __shared__ float Xs[BM][K];
    const int t = threadIdx.x;
    const int rowBase = blockIdx.x * BM;

    for (int i = t; i < BM * K; i += NB) {
        int n = i / K, k = i - n * K;
        int r = rowBase + n;
        Xs[n][k] = (r < nrows) ? X[(size_t)r * K + k] : 0.f;
    }
    __syncthreads();

    for (int i = t; i < BM * OUT; i += NB) {
        int n = i / OUT, o = i - n * OUT;
        int r = rowBase + n;
        if (r >= nrows) continue;
        float acc = b[o];
        #pragma unroll
        for (int k = 0; k < K; k += 4) {
            float4 xv = *reinterpret_cast<const float4*>(&Xs[n][k]);
            float4 wv = *reinterpret_cast<const float4*>(&W[(size_t)o * K + k]);
            acc += xv.x * wv.x + xv.y * wv.y + xv.z * wv.z + xv.w * wv.w;
        }
        if (RELU) acc = fmaxf(acc, 0.f);
        Y[(size_t)r * OUT + o] = acc;
    }
}

// ---- final dot: out[n] = H1[n][0:256] . W + b ------------------------------
__global__ __launch_bounds__(NB) void head_out_kernel(
    const float* __restrict__ X, const float* __restrict__ W,
    const float* __restrict__ b, float* __restrict__ Y, int nrows) {
    const int t = threadIdx.x;
    const int nl = t >> 4, kk = t & 15;
    const int n = blockIdx.x * 16 + nl;
    if (n >= nrows) return;
    float acc = 0.f;
    #pragma unroll
    for (int j = 0; j < 16; ++j)
        acc += X[(size_t)n * 256 + kk + 16 * j] * W[kk + 16 * j];
    #pragma unroll
    for (int off = 8; off; off >>= 1) acc += __shfl_xor(acc, off, 16);
    if (kk == 0) Y[n] = acc + b[0];
}

// ---------------------------------------------------------------------------
extern "C" void kernel_launch(void* const* d_in, const int* in_sizes, int n_in,
                              void* d_out, int out_size, void* d_ws, size_t ws_size,
                              hipStream_t stream) {
    const int*   x_layout = (const int*)d_in[0];
    const int*   x_role   = (const int*)d_in[1];
    const int*   ei       = (const int*)d_in[2];
    const float* lemb     = (const float*)d_in[3];
    const float* remb     = (const float*)d_in[4];
    const float* lin_W    = (const float*)d_in[5];
    const float* lin_b    = (const float*)d_in[6];
    const float* c0_lW    = (const float*)d_in[7];
    const float* c0_lb    = (const float*)d_in[8];
    const float* c0_rW    = (const float*)d_in[9];
    const float* c1_lW    = (const float*)d_in[10];
    const float* c1_lb    = (const float*)d_in[11];
    const float* c1_rW    = (const float*)d_in[12];
    const float* c2_lW    = (const float*)d_in[13];
    const float* c2_lb    = (const float*)d_in[14];
    const float* c2_rW    = (const float*)d_in[15];
    const float* d0_W     = (const float*)d_in[16];
    const float* d0_b     = (const float*)d_in[17];
    const float* d1_W     = (const float*)d_in[18];
    const float* d1_b     = (const float*)d_in[19];
    const float* d2_W     = (const float*)d_in[20];
    const float* d2_b     = (const float*)d_in[21];

    const int N = in_sizes[1];
    const int E = in_sizes[2] / 2;
    const int* src = ei;
    const int* dst = ei + E;

    float* ws   = (float*)d_ws;
    float* invc = ws;                       // N
    float* A    = ws + N;                   // N*96
    float* B    = A + (size_t)N * 96;       // N*96 (aggregation buffer)
    float* C    = B + (size_t)N * 96;       // N*96
    float* H0   = C + (size_t)N * 96;       // N*256
    float* H1   = A;                        // overlay: N*256 over A,B,(part of C)

    const int total = E * 96;
    const dim3 blk(NB);

    // degree counts (once)
    hipMemsetAsync(invc, 0, (size_t)N * sizeof(float), stream);
    count_kernel<<<dim3((E + NB - 1) / NB), blk, 0, stream>>>(dst, invc, E);
    invcnt_kernel<<<dim3((N + NB - 1) / NB), blk, 0, stream>>>(invc, N);

    // embed + lin -> A
    embed_lin_kernel<<<dim3((N + 31) / 32), blk, 0, stream>>>(
        x_layout, x_role, lemb, remb, lin_W, lin_b, A, N);

    const dim3 g32((N + 31) / 32);
    const dim3 gsc((total + NB - 1) / NB);

    // layer 0: A -> C
    hipMemsetAsync(B, 0, (size_t)N * 96 * sizeof(float), stream);
    scatter_add_kernel<<<gsc, blk, 0, stream>>>(A, src, dst, B, total);
    sage_gemm_kernel<96, 96, 32><<<g32, blk, 0, stream>>>(
        A, B, invc, c0_lW, c0_lb, c0_rW, C, N);

    // layer 1: C -> A
    hipMemsetAsync(B, 0, (size_t)N * 96 * sizeof(float), stream);
    scatter_add_kernel<<<gsc, blk, 0, stream>>>(C, src, dst, B, total);
    sage_gemm_kernel<96, 96, 32><<<g32, blk, 0, stream>>>(
        C, B, invc, c1_lW, c1_lb, c1_rW, A, N);

    // layer 2: A -> C
    hipMemsetAsync(B, 0, (size_t)N * 96 * sizeof(float), stream);
    scatter_add_kernel<<<gsc, blk, 0, stream>>>(A, src, dst, B, total);
    sage_gemm_kernel<96, 96, 32><<<g32, blk, 0, stream>>>(
        A, B, invc, c2_lW, c2_lb, c2_rW, C, N);

    // dense head
    gemm_bias_kernel<96, 256, 32, true><<<g32, blk, 0, stream>>>(C, d0_W, d0_b, H0, N);
    gemm_bias_kernel<256, 256, 32, true><<<g32, blk, 0, stream>>>(H0, d1_W, d1_b, H1, N);
    head_out_kernel<<<dim3((N + 15) / 16), blk, 0, stream>>>(H1, d2_W, d2_b, (float*)d_out, N);
}

// Round 2
// 1245.871 us; speedup vs baseline: 3.6869x; 3.6869x over previous
//
#include <hip/hip_runtime.h>
#include <cstddef>

// ---------------------------------------------------------------------------
// embed+concat -> Linear(80->96) -> 3x SAGEConv(96, mean) -> MLP(96->256->256->1)
// fp32. N = in_sizes[1], E = in_sizes[2]/2.
// Round 1: register-tiled SGEMM for all dense layers (W staged in LDS).
// ---------------------------------------------------------------------------

#define NB 256

// ---- degree count ----------------------------------------------------------
__global__ __launch_bounds__(NB) void count_kernel(const int* __restrict__ dst,
                                                   float* __restrict__ cnt, int E) {
    int e = blockIdx.x * NB + threadIdx.x;
    if (e < E) atomicAdd(&cnt[dst[e]], 1.0f);
}

__global__ __launch_bounds__(NB) void invcnt_kernel(float* __restrict__ cnt, int n) {
    int i = blockIdx.x * NB + threadIdx.x;
    if (i < n) cnt[i] = 1.0f / fmaxf(cnt[i], 1.0f);
}

// ---- embedding gather: F[n][0:80] = [lay(4x16) | role(16)] -----------------
__global__ __launch_bounds__(NB) void gather_feat_kernel(
    const int* __restrict__ xl, const int* __restrict__ xr,
    const float* __restrict__ lemb, const float* __restrict__ remb,
    float* __restrict__ F, int total /* N*80 */) {
    int i = blockIdx.x * NB + threadIdx.x;
    if (i >= total) return;
    int n = i / 80;
    int j = i - n * 80;
    float v;
    if (j < 64) {
        int l = j >> 4, c = j & 15;
        v = lemb[(size_t)xl[n * 4 + l] * 16 + c];
    } else {
        v = remb[(size_t)xr[n] * 16 + (j - 64)];
    }
    F[i] = v;
}

// ---- scatter-add of messages (per edge,channel) ----------------------------
__global__ __launch_bounds__(NB) void scatter_add_kernel(
    const float* __restrict__ X, const int* __restrict__ src,
    const int* __restrict__ dst, float* __restrict__ G, int total) {
    int i = blockIdx.x * NB + threadIdx.x;
    if (i >= total) return;
    int e = i / 96;
    int c = i - e * 96;
    atomicAdd(&G[(size_t)dst[e] * 96 + c], X[(size_t)src[e] * 96 + c]);
}

// ---- register-tiled GEMM: Y = act(X @ Wx^T [+ (G*invc) @ Wg^T] + bias) -----
// X:[nrows,K] Wx:[OUT,K] (Wg same for SAGE). Grid: (ceil(nrows/BM), OUT/BN).
// 256 threads as 16x16; thread (tx,ty) computes TM x TN outputs.
template <int K, int OUT, int BM, int BN, int TM, int TN, bool RELU, bool SAGE>
__global__ __launch_bounds__(NB) void gemm_rt(
    const float* __restrict__ X, const float* __restrict__ G,
    const float* __restrict__ invc,
    const float* __restrict__ Wx, const float* __restrict__ Wg,
    const float* __restrict__ bias, float* __restrict__ Y, int nrows) {
    constexpr int BK = 16;
    constexpr int KT = SAGE ? 2 * K : K;
    __shared__ float Xs[BK][BM + 4];
    __shared__ float Ws[BK][BN + 4];

    const int t = threadIdx.x;
    const int tx = t & 15, ty = t >> 4;
    const int rowBase = blockIdx.x * BM;
    const int colBase = blockIdx.y * BN;

    float acc[TM][TN];
#pragma unroll
    for (int i = 0; i < TM; ++i)
#pragma unroll
        for (int j = 0; j < TN; ++j) acc[i][j] = 0.f;

    for (int k0 = 0; k0 < KT; k0 += BK) {
        const bool isG = SAGE && (k0 >= K);
        const float* __restrict__ Xp = isG ? G : X;
        const float* __restrict__ Wp = isG ? Wg : Wx;
        const int kl = isG ? (k0 - K) : k0;

        // X tile -> Xs[k][m] (transposed)
        for (int v = t; v < BM * BK / 4; v += NB) {
            int m = v >> 2, q = v & 3;
            int r = rowBase + m;
            float4 f = {0.f, 0.f, 0.f, 0.f};
            if (r < nrows) {
                f = *reinterpret_cast<const float4*>(&Xp[(size_t)r * K + kl + 4 * q]);
                if (isG) {
                    float ic = invc[r];
                    f.x *= ic; f.y *= ic; f.z *= ic; f.w *= ic;
                }
            }
            Xs[4 * q + 0][m] = f.x;
            Xs[4 * q + 1][m] = f.y;
            Xs[4 * q + 2][m] = f.z;
            Xs[4 * q + 3][m] = f.w;
        }
        // W tile -> Ws[k][n] (transposed)
        for (int v = t; v < BN * BK / 4; v += NB) {
            int n = v >> 2, q = v & 3;
            float4 f = *reinterpret_cast<const float4*>(
                &Wp[(size_t)(colBase + n) * K + kl + 4 * q]);
            Ws[4 * q + 0][n] = f.x;
            Ws[4 * q + 1][n] = f.y;
            Ws[4 * q + 2][n] = f.z;
            Ws[4 * q + 3][n] = f.w;
        }
        __syncthreads();

#pragma unroll
        for (int k = 0; k < BK; ++k) {
            float a[TM], b[TN];
#pragma unroll
            for (int i = 0; i < TM; ++i) a[i] = Xs[k][ty * TM + i];
#pragma unroll
            for (int j = 0; j < TN; ++j) b[j] = Ws[k][tx * TN + j];
#pragma unroll
            for (int i = 0; i < TM; ++i)
#pragma unroll
                for (int j = 0; j < TN; ++j) acc[i][j] += a[i] * b[j];
        }
        __syncthreads();
    }

#pragma unroll
    for (int i = 0; i < TM; ++i) {
        int r = rowBase + ty * TM + i;
        if (r >= nrows) continue;
#pragma unroll
        for (int j = 0; j < TN; ++j) {
            float v = acc[i][j] + bias[colBase + tx * TN + j];
            if (RELU) v = fmaxf(v, 0.f);
            Y[(size_t)r * OUT + colBase + tx * TN + j] = v;
        }
    }
}

// ---- final dot: out[n] = H1[n][0:256] . W + b ------------------------------
__global__ __launch_bounds__(NB) void head_out_kernel(
    const float* __restrict__ X, const float* __restrict__ W,
    const float* __restrict__ b, float* __restrict__ Y, int nrows) {
    const int t = threadIdx.x;
    const int lane = t & 63, nl = t >> 6;
    const int n = blockIdx.x * 4 + nl;
    if (n >= nrows) return;
    float4 xv = *reinterpret_cast<const float4*>(&X[(size_t)n * 256 + lane * 4]);
    float4 wv = *reinterpret_cast<const float4*>(&W[lane * 4]);
    float acc = xv.x * wv.x + xv.y * wv.y + xv.z * wv.z + xv.w * wv.w;
#pragma unroll
    for (int off = 32; off; off >>= 1) acc += __shfl_xor(acc, off);
    if (lane == 0) Y[n] = acc + b[0];
}

// ---------------------------------------------------------------------------
extern "C" void kernel_launch(void* const* d_in, const int* in_sizes, int n_in,
                              void* d_out, int out_size, void* d_ws, size_t ws_size,
                              hipStream_t stream) {
    const int*   x_layout = (const int*)d_in[0];
    const int*   x_role   = (const int*)d_in[1];
    const int*   ei       = (const int*)d_in[2];
    const float* lemb     = (const float*)d_in[3];
    const float* remb     = (const float*)d_in[4];
    const float* lin_W    = (const float*)d_in[5];
    const float* lin_b    = (const float*)d_in[6];
    const float* c0_lW    = (const float*)d_in[7];
    const float* c0_lb    = (const float*)d_in[8];
    const float* c0_rW    = (const float*)d_in[9];
    const float* c1_lW    = (const float*)d_in[10];
    const float* c1_lb    = (const float*)d_in[11];
    const float* c1_rW    = (const float*)d_in[12];
    const float* c2_lW    = (const float*)d_in[13];
    const float* c2_lb    = (const float*)d_in[14];
    const float* c2_rW    = (const float*)d_in[15];
    const float* d0_W     = (const float*)d_in[16];
    const float* d0_b     = (const float*)d_in[17];
    const float* d1_W     = (const float*)d_in[18];
    const float* d1_b     = (const float*)d_in[19];
    const float* d2_W     = (const float*)d_in[20];
    const float* d2_b     = (const float*)d_in[21];

    const int N = in_sizes[1];
    const int E = in_sizes[2] / 2;
    const int* src = ei;
    const int* dst = ei + E;

    // workspace layout (floats):
    //   invc[N] | A[N*96] | B[N*96] | C[N*96] | H0[N*256]
    //   F (N*80) overlays H0 (dead before d0); H1 (N*256) overlays A+B+C.
    float* ws   = (float*)d_ws;
    float* invc = ws;
    float* A    = ws + N;
    float* B    = A + (size_t)N * 96;
    float* C    = B + (size_t)N * 96;
    float* H0   = C + (size_t)N * 96;
    float* F    = H0;
    float* H1   = A;

    const dim3 blk(NB);
    const int rowTiles = (N + 127) / 128;

    // degree counts (once per call)
    hipMemsetAsync(invc, 0, (size_t)N * sizeof(float), stream);
    count_kernel<<<dim3((E + NB - 1) / NB), blk, 0, stream>>>(dst, invc, E);
    invcnt_kernel<<<dim3((N + NB - 1) / NB), blk, 0, stream>>>(invc, N);

    // embedding gather -> F, then Linear(80->96) -> A
    gather_feat_kernel<<<dim3((N * 80 + NB - 1) / NB), blk, 0, stream>>>(
        x_layout, x_role, lemb, remb, F, N * 80);
    gemm_rt<80, 96, 128, 96, 8, 6, false, false><<<dim3(rowTiles, 1), blk, 0, stream>>>(
        F, nullptr, nullptr, lin_W, nullptr, lin_b, A, N);

    const dim3 gsc(((size_t)E * 96 + NB - 1) / NB);

    // layer 0: A -> C
    hipMemsetAsync(B, 0, (size_t)N * 96 * sizeof(float), stream);
    scatter_add_kernel<<<gsc, blk, 0, stream>>>(A, src, dst, B, E * 96);
    gemm_rt<96, 96, 128, 96, 8, 6, true, true><<<dim3(rowTiles, 1), blk, 0, stream>>>(
        A, B, invc, c0_rW, c0_lW, c0_lb, C, N);

    // layer 1: C -> A
    hipMemsetAsync(B, 0, (size_t)N * 96 * sizeof(float), stream);
    scatter_add_kernel<<<gsc, blk, 0, stream>>>(C, src, dst, B, E * 96);
    gemm_rt<96, 96, 128, 96, 8, 6, true, true><<<dim3(rowTiles, 1), blk, 0, stream>>>(
        C, B, invc, c1_rW, c1_lW, c1_lb, A, N);

    // layer 2: A -> C
    hipMemsetAsync(B, 0, (size_t)N * 96 * sizeof(float), stream);
    scatter_add_kernel<<<gsc, blk, 0, stream>>>(A, src, dst, B, E * 96);
    gemm_rt<96, 96, 128, 96, 8, 6, true, true><<<dim3(rowTiles, 1), blk, 0, stream>>>(
        A, B, invc, c2_rW, c2_lW, c2_lb, C, N);

    // dense head
    gemm_rt<96, 256, 128, 64, 8, 4, true, false><<<dim3(rowTiles, 4), blk, 0, stream>>>(
        C, nullptr, nullptr, d0_W, nullptr, d0_b, H0, N);
    gemm_rt<256, 256, 128, 64, 8, 4, true, false><<<dim3(rowTiles, 4), blk, 0, stream>>>(
        H0, nullptr, nullptr, d1_W, nullptr, d1_b, H1, N);
    head_out_kernel<<<dim3((N + 3) / 4), blk, 0, stream>>>(
        H1, d2_W, d2_b, (float*)d_out, N);
}

// Round 3
// 698.481 us; speedup vs baseline: 6.5763x; 1.7837x over previous
//
#include <hip/hip_runtime.h>
#include <cstddef>

// ---------------------------------------------------------------------------
// embed+concat -> Linear(80->96) -> 3x SAGEConv(96, mean) -> MLP(96->256->256->1)
// fp32. N = in_sizes[1], E = in_sizes[2]/2.
// Round 2: CSR build + gather-mean aggregation (kills fp32 atomic scatter).
// ---------------------------------------------------------------------------

#define NB 256

// ---- CSR: count in-degree --------------------------------------------------
__global__ __launch_bounds__(NB) void count_int_kernel(const int* __restrict__ dst,
                                                       int* __restrict__ cnt, int E) {
    int e = blockIdx.x * NB + threadIdx.x;
    if (e < E) atomicAdd(&cnt[dst[e]], 1);
}

// ---- CSR: single-block exclusive scan (N up to ~8M) ------------------------
// 1024 threads, 8 elements/thread/chunk. Writes rowptr[0..n] and cursor[0..n-1].
__global__ __launch_bounds__(1024) void scan_kernel(const int* __restrict__ cnt,
                                                    int* __restrict__ rowptr,
                                                    int* __restrict__ cursor, int n) {
    __shared__ int buf[1024];
    __shared__ int carry;
    const int tid = threadIdx.x;
    if (tid == 0) carry = 0;
    __syncthreads();
    const int CH = 1024 * 8;
    for (int base = 0; base < n; base += CH) {
        int loc[8];
        int s = 0;
        #pragma unroll
        for (int q = 0; q < 8; ++q) {
            int i = base + tid * 8 + q;
            int v = (i < n) ? cnt[i] : 0;
            loc[q] = s;
            s += v;
        }
        buf[tid] = s;
        __syncthreads();
        // Hillis-Steele inclusive scan over 1024 partials
        for (int off = 1; off < 1024; off <<= 1) {
            int t = (tid >= off) ? buf[tid - off] : 0;
            __syncthreads();
            buf[tid] += t;
            __syncthreads();
        }
        int tpref = carry + buf[tid] - s;  // exclusive prefix for this thread
        #pragma unroll
        for (int q = 0; q < 8; ++q) {
            int i = base + tid * 8 + q;
            if (i < n) {
                int v = tpref + loc[q];
                rowptr[i] = v;
                cursor[i] = v;
            }
        }
        int chunk = buf[1023];
        __syncthreads();
        if (tid == 0) carry += chunk;
        __syncthreads();
    }
    if (tid == 0) rowptr[n] = carry;
}

// ---- CSR: fill column (src) list -------------------------------------------
__global__ __launch_bounds__(NB) void fill_csr_kernel(const int* __restrict__ src,
                                                      const int* __restrict__ dst,
                                                      int* __restrict__ cursor,
                                                      int* __restrict__ col, int E) {
    int e = blockIdx.x * NB + threadIdx.x;
    if (e >= E) return;
    int p = atomicAdd(&cursor[dst[e]], 1);
    col[p] = src[e];
}

// ---- gather-mean: G[n] = mean_{j in col[rowptr[n]:rowptr[n+1]]} X[j] -------
// 24 threads per node, one float4 chunk each (96 = 24*4).
__global__ __launch_bounds__(NB) void gather_mean_kernel(
    const float* __restrict__ X, const int* __restrict__ rowptr,
    const int* __restrict__ col, float* __restrict__ G, int N) {
    int idx = blockIdx.x * NB + threadIdx.x;
    int node = idx / 24;
    if (node >= N) return;
    int c = idx - node * 24;
    const int s = rowptr[node], pe = rowptr[node + 1];
    float4 acc = {0.f, 0.f, 0.f, 0.f};
    int p = s;
    for (; p + 1 < pe; p += 2) {
        int j0 = col[p], j1 = col[p + 1];
        float4 v0 = *reinterpret_cast<const float4*>(&X[(size_t)j0 * 96 + 4 * c]);
        float4 v1 = *reinterpret_cast<const float4*>(&X[(size_t)j1 * 96 + 4 * c]);
        acc.x += v0.x + v1.x; acc.y += v0.y + v1.y;
        acc.z += v0.z + v1.z; acc.w += v0.w + v1.w;
    }
    if (p < pe) {
        int j = col[p];
        float4 v = *reinterpret_cast<const float4*>(&X[(size_t)j * 96 + 4 * c]);
        acc.x += v.x; acc.y += v.y; acc.z += v.z; acc.w += v.w;
    }
    int deg = pe - s;
    float inv = (deg > 0) ? 1.f / (float)deg : 0.f;
    acc.x *= inv; acc.y *= inv; acc.z *= inv; acc.w *= inv;
    *reinterpret_cast<float4*>(&G[(size_t)node * 96 + 4 * c]) = acc;
}

// ---- embedding gather: F[n][0:80] = [lay(4x16) | role(16)] -----------------
__global__ __launch_bounds__(NB) void gather_feat_kernel(
    const int* __restrict__ xl, const int* __restrict__ xr,
    const float* __restrict__ lemb, const float* __restrict__ remb,
    float* __restrict__ F, int total /* N*80 */) {
    int i = blockIdx.x * NB + threadIdx.x;
    if (i >= total) return;
    int n = i / 80;
    int j = i - n * 80;
    float v;
    if (j < 64) {
        int l = j >> 4, c = j & 15;
        v = lemb[(size_t)xl[n * 4 + l] * 16 + c];
    } else {
        v = remb[(size_t)xr[n] * 16 + (j - 64)];
    }
    F[i] = v;
}

// ---- register-tiled GEMM: Y = act(X @ Wx^T [+ G @ Wg^T] + bias) ------------
// Grid: (ceil(nrows/BM), OUT/BN). 256 threads as 16x16, TMxTN per thread.
template <int K, int OUT, int BM, int BN, int TM, int TN, bool RELU, bool SAGE>
__global__ __launch_bounds__(NB) void gemm_rt(
    const float* __restrict__ X, const float* __restrict__ G,
    const float* __restrict__ Wx, const float* __restrict__ Wg,
    const float* __restrict__ bias, float* __restrict__ Y, int nrows) {
    constexpr int BK = 16;
    constexpr int KT = SAGE ? 2 * K : K;
    __shared__ float Xs[BK][BM + 4];
    __shared__ float Ws[BK][BN + 4];

    const int t = threadIdx.x;
    const int tx = t & 15, ty = t >> 4;
    const int rowBase = blockIdx.x * BM;
    const int colBase = blockIdx.y * BN;

    float acc[TM][TN];
#pragma unroll
    for (int i = 0; i < TM; ++i)
#pragma unroll
        for (int j = 0; j < TN; ++j) acc[i][j] = 0.f;

    for (int k0 = 0; k0 < KT; k0 += BK) {
        const bool isG = SAGE && (k0 >= K);
        const float* __restrict__ Xp = isG ? G : X;
        const float* __restrict__ Wp = isG ? Wg : Wx;
        const int kl = isG ? (k0 - K) : k0;

        for (int v = t; v < BM * BK / 4; v += NB) {
            int m = v >> 2, q = v & 3;
            int r = rowBase + m;
            float4 f = {0.f, 0.f, 0.f, 0.f};
            if (r < nrows)
                f = *reinterpret_cast<const float4*>(&Xp[(size_t)r * K + kl + 4 * q]);
            Xs[4 * q + 0][m] = f.x;
            Xs[4 * q + 1][m] = f.y;
            Xs[4 * q + 2][m] = f.z;
            Xs[4 * q + 3][m] = f.w;
        }
        for (int v = t; v < BN * BK / 4; v += NB) {
            int n = v >> 2, q = v & 3;
            float4 f = *reinterpret_cast<const float4*>(
                &Wp[(size_t)(colBase + n) * K + kl + 4 * q]);
            Ws[4 * q + 0][n] = f.x;
            Ws[4 * q + 1][n] = f.y;
            Ws[4 * q + 2][n] = f.z;
            Ws[4 * q + 3][n] = f.w;
        }
        __syncthreads();

#pragma unroll
        for (int k = 0; k < BK; ++k) {
            float a[TM], b[TN];
#pragma unroll
            for (int i = 0; i < TM; ++i) a[i] = Xs[k][ty * TM + i];
#pragma unroll
            for (int j = 0; j < TN; ++j) b[j] = Ws[k][tx * TN + j];
#pragma unroll
            for (int i = 0; i < TM; ++i)
#pragma unroll
                for (int j = 0; j < TN; ++j) acc[i][j] += a[i] * b[j];
        }
        __syncthreads();
    }

#pragma unroll
    for (int i = 0; i < TM; ++i) {
        int r = rowBase + ty * TM + i;
        if (r >= nrows) continue;
#pragma unroll
        for (int j = 0; j < TN; ++j) {
            float v = acc[i][j] + bias[colBase + tx * TN + j];
            if (RELU) v = fmaxf(v, 0.f);
            Y[(size_t)r * OUT + colBase + tx * TN + j] = v;
        }
    }
}

// ---- final dot: out[n] = H1[n][0:256] . W + b ------------------------------
__global__ __launch_bounds__(NB) void head_out_kernel(
    const float* __restrict__ X, const float* __restrict__ W,
    const float* __restrict__ b, float* __restrict__ Y, int nrows) {
    const int t = threadIdx.x;
    const int lane = t & 63, nl = t >> 6;
    const int n = blockIdx.x * 4 + nl;
    if (n >= nrows) return;
    float4 xv = *reinterpret_cast<const float4*>(&X[(size_t)n * 256 + lane * 4]);
    float4 wv = *reinterpret_cast<const float4*>(&W[lane * 4]);
    float acc = xv.x * wv.x + xv.y * wv.y + xv.z * wv.z + xv.w * wv.w;
#pragma unroll
    for (int off = 32; off; off >>= 1) acc += __shfl_xor(acc, off);
    if (lane == 0) Y[n] = acc + b[0];
}

// ---------------------------------------------------------------------------
extern "C" void kernel_launch(void* const* d_in, const int* in_sizes, int n_in,
                              void* d_out, int out_size, void* d_ws, size_t ws_size,
                              hipStream_t stream) {
    const int*   x_layout = (const int*)d_in[0];
    const int*   x_role   = (const int*)d_in[1];
    const int*   ei       = (const int*)d_in[2];
    const float* lemb     = (const float*)d_in[3];
    const float* remb     = (const float*)d_in[4];
    const float* lin_W    = (const float*)d_in[5];
    const float* lin_b    = (const float*)d_in[6];
    const float* c0_lW    = (const float*)d_in[7];
    const float* c0_lb    = (const float*)d_in[8];
    const float* c0_rW    = (const float*)d_in[9];
    const float* c1_lW    = (const float*)d_in[10];
    const float* c1_lb    = (const float*)d_in[11];
    const float* c1_rW    = (const float*)d_in[12];
    const float* c2_lW    = (const float*)d_in[13];
    const float* c2_lb    = (const float*)d_in[14];
    const float* c2_rW    = (const float*)d_in[15];
    const float* d0_W     = (const float*)d_in[16];
    const float* d0_b     = (const float*)d_in[17];
    const float* d1_W     = (const float*)d_in[18];
    const float* d1_b     = (const float*)d_in[19];
    const float* d2_W     = (const float*)d_in[20];
    const float* d2_b     = (const float*)d_in[21];

    const int N = in_sizes[1];
    const int E = in_sizes[2] / 2;
    const int* src = ei;
    const int* dst = ei + E;

    // workspace layout (all 4-byte elems):
    //   region R0 = 256N floats: early it holds [rowptr(N+1) | cursor(N) | col(E) | F(80N)],
    //               late it holds H0 (256N) for the MLP head (CSR+F dead by then).
    //   then A(96N) | B(96N) | C(96N). H1 (256N) overlays A..C during d1/head.
    float* ws     = (float*)d_ws;
    float* H0     = ws;
    int*   rowptr = (int*)d_ws;
    int*   cursor = rowptr + (N + 1);
    int*   col    = cursor + N;
    size_t intCnt = ((size_t)(N + 1) + N + E + 3) & ~(size_t)3;  // align to 16B
    float* F      = ws + intCnt;
    float* A      = ws + (size_t)256 * N;
    float* B      = A + (size_t)96 * N;
    float* C      = B + (size_t)96 * N;
    float* H1     = A;

    const dim3 blk(NB);
    const int rowTiles = (N + 127) / 128;
    const dim3 gE((E + NB - 1) / NB);
    const dim3 gGather(((size_t)N * 24 + NB - 1) / NB);

    // ---- CSR build (per call; ws is re-poisoned before every launch) ----
    hipMemsetAsync(cursor, 0, (size_t)N * sizeof(int), stream);
    count_int_kernel<<<gE, blk, 0, stream>>>(dst, cursor, E);
    scan_kernel<<<dim3(1), dim3(1024), 0, stream>>>(cursor, rowptr, cursor, N);
    fill_csr_kernel<<<gE, blk, 0, stream>>>(src, dst, cursor, col, E);

    // ---- embed + lin -> A ----
    gather_feat_kernel<<<dim3(((size_t)N * 80 + NB - 1) / NB), blk, 0, stream>>>(
        x_layout, x_role, lemb, remb, F, N * 80);
    gemm_rt<80, 96, 128, 96, 8, 6, false, false><<<dim3(rowTiles, 1), blk, 0, stream>>>(
        F, nullptr, lin_W, nullptr, lin_b, A, N);

    // ---- layer 0: A -> C ----
    gather_mean_kernel<<<gGather, blk, 0, stream>>>(A, rowptr, col, B, N);
    gemm_rt<96, 96, 128, 96, 8, 6, true, true><<<dim3(rowTiles, 1), blk, 0, stream>>>(
        A, B, c0_rW, c0_lW, c0_lb, C, N);

    // ---- layer 1: C -> A ----
    gather_mean_kernel<<<gGather, blk, 0, stream>>>(C, rowptr, col, B, N);
    gemm_rt<96, 96, 128, 96, 8, 6, true, true><<<dim3(rowTiles, 1), blk, 0, stream>>>(
        C, B, c1_rW, c1_lW, c1_lb, A, N);

    // ---- layer 2: A -> C ----
    gather_mean_kernel<<<gGather, blk, 0, stream>>>(A, rowptr, col, B, N);
    gemm_rt<96, 96, 128, 96, 8, 6, true, true><<<dim3(rowTiles, 1), blk, 0, stream>>>(
        A, B, c2_rW, c2_lW, c2_lb, C, N);

    // ---- dense head ----
    gemm_rt<96, 256, 128, 64, 8, 4, true, false><<<dim3(rowTiles, 4), blk, 0, stream>>>(
        C, nullptr, d0_W, nullptr, d0_b, H0, N);
    gemm_rt<256, 256, 128, 64, 8, 4, true, false><<<dim3(rowTiles, 4), blk, 0, stream>>>(
        H0, nullptr, d1_W, nullptr, d1_b, H1, N);
    head_out_kernel<<<dim3((N + 3) / 4), blk, 0, stream>>>(
        H1, d2_W, d2_b, (float*)d_out, N);
}

// Round 5
// 693.769 us; speedup vs baseline: 6.6209x; 1.0068x over previous
//
#include <hip/hip_runtime.h>
#include <cstddef>

// ---------------------------------------------------------------------------
// embed+concat -> Linear(80->96) -> 3x SAGEConv(96, mean) -> MLP(96->256->256->1)
// fp32. N = in_sizes[1], E = in_sizes[2]/2.
// Round 3 (resubmit, unmeasured): fuse d2 into d1 (atomic dot epilogue),
// fuse embedding into lin GEMM, 1D col-fastest grid, TN=8 head micro-tile.
// ---------------------------------------------------------------------------

#define NB 256

// ---- CSR: count in-degree --------------------------------------------------
__global__ __launch_bounds__(NB) void count_int_kernel(const int* __restrict__ dst,
                                                       int* __restrict__ cnt, int E) {
    int e = blockIdx.x * NB + threadIdx.x;
    if (e < E) atomicAdd(&cnt[dst[e]], 1);
}

// ---- CSR: single-block exclusive scan --------------------------------------
__global__ __launch_bounds__(1024) void scan_kernel(const int* __restrict__ cnt,
                                                    int* __restrict__ rowptr,
                                                    int* __restrict__ cursor, int n) {
    __shared__ int buf[1024];
    __shared__ int carry;
    const int tid = threadIdx.x;
    if (tid == 0) carry = 0;
    __syncthreads();
    const int CH = 1024 * 8;
    for (int base = 0; base < n; base += CH) {
        int loc[8];
        int s = 0;
        #pragma unroll
        for (int q = 0; q < 8; ++q) {
            int i = base + tid * 8 + q;
            int v = (i < n) ? cnt[i] : 0;
            loc[q] = s;
            s += v;
        }
        buf[tid] = s;
        __syncthreads();
        for (int off = 1; off < 1024; off <<= 1) {
            int t = (tid >= off) ? buf[tid - off] : 0;
            __syncthreads();
            buf[tid] += t;
            __syncthreads();
        }
        int tpref = carry + buf[tid] - s;
        #pragma unroll
        for (int q = 0; q < 8; ++q) {
            int i = base + tid * 8 + q;
            if (i < n) {
                int v = tpref + loc[q];
                rowptr[i] = v;
                cursor[i] = v;
            }
        }
        int chunk = buf[1023];
        __syncthreads();
        if (tid == 0) carry += chunk;
        __syncthreads();
    }
    if (tid == 0) rowptr[n] = carry;
}

// ---- CSR: fill column (src) list -------------------------------------------
__global__ __launch_bounds__(NB) void fill_csr_kernel(const int* __restrict__ src,
                                                      const int* __restrict__ dst,
                                                      int* __restrict__ cursor,
                                                      int* __restrict__ col, int E) {
    int e = blockIdx.x * NB + threadIdx.x;
    if (e >= E) return;
    int p = atomicAdd(&cursor[dst[e]], 1);
    col[p] = src[e];
}

// ---- gather-mean: G[n] = mean_{j in col[rowptr[n]:rowptr[n+1]]} X[j] -------
__global__ __launch_bounds__(NB) void gather_mean_kernel(
    const float* __restrict__ X, const int* __restrict__ rowptr,
    const int* __restrict__ col, float* __restrict__ G, int N) {
    int idx = blockIdx.x * NB + threadIdx.x;
    int node = idx / 24;
    if (node >= N) return;
    int c = idx - node * 24;
    const int s = rowptr[node], pe = rowptr[node + 1];
    float4 acc = {0.f, 0.f, 0.f, 0.f};
    int p = s;
    for (; p + 1 < pe; p += 2) {
        int j0 = col[p], j1 = col[p + 1];
        float4 v0 = *reinterpret_cast<const float4*>(&X[(size_t)j0 * 96 + 4 * c]);
        float4 v1 = *reinterpret_cast<const float4*>(&X[(size_t)j1 * 96 + 4 * c]);
        acc.x += v0.x + v1.x; acc.y += v0.y + v1.y;
        acc.z += v0.z + v1.z; acc.w += v0.w + v1.w;
    }
    if (p < pe) {
        int j = col[p];
        float4 v = *reinterpret_cast<const float4*>(&X[(size_t)j * 96 + 4 * c]);
        acc.x += v.x; acc.y += v.y; acc.z += v.z; acc.w += v.w;
    }
    int deg = pe - s;
    float inv = (deg > 0) ? 1.f / (float)deg : 0.f;
    acc.x *= inv; acc.y *= inv; acc.z *= inv; acc.w *= inv;
    *reinterpret_cast<float4*>(&G[(size_t)node * 96 + 4 * c]) = acc;
}

// ---- register-tiled GEMM ---------------------------------------------------
// Y = act(X @ Wx^T [+ G @ Wg^T] + bias); EMB: X-load gathers embeddings;
// FDOT: epilogue computes out[r] += relu(row) . d2w (atomicAdd), Y == out[N].
// Grid 1D: (rowTiles * CT), col-tile fastest. 256 thr as 16x16, TMxTN each.
template <int K, int OUT, int BM, int BN, int TM, int TN,
          bool RELU, bool SAGE, bool EMB, bool FDOT>
__global__ __launch_bounds__(NB) void gemm2(
    const float* __restrict__ X, const float* __restrict__ G,
    const float* __restrict__ Wx, const float* __restrict__ Wg,
    const float* __restrict__ bias,
    const int* __restrict__ xl, const int* __restrict__ xr,
    const float* __restrict__ lemb, const float* __restrict__ remb,
    const float* __restrict__ d2w, const float* __restrict__ d2b,
    float* __restrict__ Y, int nrows) {
    constexpr int BK = 16;
    constexpr int CT = OUT / BN;
    constexpr int KT = SAGE ? 2 * K : K;
    __shared__ float Xs[BK][BM + 4];
    __shared__ float Ws[BK][BN + 4];

    const int t = threadIdx.x;
    const int tx = t & 15, ty = t >> 4;
    const int bid = blockIdx.x;
    const int rowBase = (bid / CT) * BM;
    const int colTile = bid % CT;
    const int colBase = colTile * BN;

    float acc[TM][TN];
#pragma unroll
    for (int i = 0; i < TM; ++i)
#pragma unroll
        for (int j = 0; j < TN; ++j) acc[i][j] = 0.f;

    for (int k0 = 0; k0 < KT; k0 += BK) {
        const bool isG = SAGE && (k0 >= K);
        const float* __restrict__ Xp = isG ? G : X;
        const float* __restrict__ Wp = isG ? Wg : Wx;
        const int kl = isG ? (k0 - K) : k0;

        // X tile -> Xs[k][m] (transposed)
        for (int v = t; v < BM * BK / 4; v += NB) {
            int m = v >> 2, q = v & 3;
            int r = rowBase + m;
            float4 f = {0.f, 0.f, 0.f, 0.f};
            if (r < nrows) {
                if (EMB) {
                    int kk = kl + 4 * q;
                    if (kk < 64) {
                        int l = kk >> 4, c = kk & 15;
                        f = *reinterpret_cast<const float4*>(
                            &lemb[(size_t)xl[r * 4 + l] * 16 + c]);
                    } else {
                        f = *reinterpret_cast<const float4*>(
                            &remb[(size_t)xr[r] * 16 + (kk - 64)]);
                    }
                } else {
                    f = *reinterpret_cast<const float4*>(&Xp[(size_t)r * K + kl + 4 * q]);
                }
            }
            Xs[4 * q + 0][m] = f.x;
            Xs[4 * q + 1][m] = f.y;
            Xs[4 * q + 2][m] = f.z;
            Xs[4 * q + 3][m] = f.w;
        }
        // W tile -> Ws[k][n] (transposed)
        for (int v = t; v < BN * BK / 4; v += NB) {
            int n = v >> 2, q = v & 3;
            float4 f = *reinterpret_cast<const float4*>(
                &Wp[(size_t)(colBase + n) * K + kl + 4 * q]);
            Ws[4 * q + 0][n] = f.x;
            Ws[4 * q + 1][n] = f.y;
            Ws[4 * q + 2][n] = f.z;
            Ws[4 * q + 3][n] = f.w;
        }
        __syncthreads();

#pragma unroll
        for (int k = 0; k < BK; ++k) {
            float a[TM], b[TN];
#pragma unroll
            for (int i = 0; i < TM; ++i) a[i] = Xs[k][ty * TM + i];
#pragma unroll
            for (int j = 0; j < TN; ++j) b[j] = Ws[k][tx * TN + j];
#pragma unroll
            for (int i = 0; i < TM; ++i)
#pragma unroll
                for (int j = 0; j < TN; ++j) acc[i][j] += a[i] * b[j];
        }
        __syncthreads();
    }

    if (!FDOT) {
#pragma unroll
        for (int i = 0; i < TM; ++i) {
            int r = rowBase + ty * TM + i;
            if (r >= nrows) continue;
#pragma unroll
            for (int j = 0; j < TN; ++j) {
                float v = acc[i][j] + bias[colBase + tx * TN + j];
                if (RELU) v = fmaxf(v, 0.f);
                Y[(size_t)r * OUT + colBase + tx * TN + j] = v;
            }
        }
    } else {
#pragma unroll
        for (int i = 0; i < TM; ++i) {
            int r = rowBase + ty * TM + i;
            float p = 0.f;
#pragma unroll
            for (int j = 0; j < TN; ++j) {
                float v = acc[i][j] + bias[colBase + tx * TN + j];
                v = fmaxf(v, 0.f);
                p += v * d2w[colBase + tx * TN + j];
            }
#pragma unroll
            for (int off = 1; off < 16; off <<= 1) p += __shfl_xor(p, off);
            if (tx == 0 && r < nrows)
                atomicAdd(&Y[r], p + (colTile == 0 ? d2b[0] : 0.f));
        }
    }
}

// ---------------------------------------------------------------------------
extern "C" void kernel_launch(void* const* d_in, const int* in_sizes, int n_in,
                              void* d_out, int out_size, void* d_ws, size_t ws_size,
                              hipStream_t stream) {
    const int*   x_layout = (const int*)d_in[0];
    const int*   x_role   = (const int*)d_in[1];
    const int*   ei       = (const int*)d_in[2];
    const float* lemb     = (const float*)d_in[3];
    const float* remb     = (const float*)d_in[4];
    const float* lin_W    = (const float*)d_in[5];
    const float* lin_b    = (const float*)d_in[6];
    const float* c0_lW    = (const float*)d_in[7];
    const float* c0_lb    = (const float*)d_in[8];
    const float* c0_rW    = (const float*)d_in[9];
    const float* c1_lW    = (const float*)d_in[10];
    const float* c1_lb    = (const float*)d_in[11];
    const float* c1_rW    = (const float*)d_in[12];
    const float* c2_lW    = (const float*)d_in[13];
    const float* c2_lb    = (const float*)d_in[14];
    const float* c2_rW    = (const float*)d_in[15];
    const float* d0_W     = (const float*)d_in[16];
    const float* d0_b     = (const float*)d_in[17];
    const float* d1_W     = (const float*)d_in[18];
    const float* d1_b     = (const float*)d_in[19];
    const float* d2_W     = (const float*)d_in[20];
    const float* d2_b     = (const float*)d_in[21];

    const int N = in_sizes[1];
    const int E = in_sizes[2] / 2;
    const int* src = ei;
    const int* dst = ei + E;

    // workspace (4-byte elems):
    //   R0 (256N): early = [rowptr(N+1)|cursor(N)|col(E)]; late = H0(256N)
    //   then A(96N) | B(96N) | C(96N)
    float* ws     = (float*)d_ws;
    float* H0     = ws;
    int*   rowptr = (int*)d_ws;
    int*   cursor = rowptr + (N + 1);
    int*   col    = cursor + N;
    float* A      = ws + (size_t)256 * N;
    float* B      = A + (size_t)96 * N;
    float* C      = B + (size_t)96 * N;

    const dim3 blk(NB);
    const int rowTiles = (N + 127) / 128;
    const dim3 gE((E + NB - 1) / NB);
    const dim3 gGather(((size_t)N * 24 + NB - 1) / NB);

    // ---- CSR build ----
    hipMemsetAsync(cursor, 0, (size_t)N * sizeof(int), stream);
    count_int_kernel<<<gE, blk, 0, stream>>>(dst, cursor, E);
    scan_kernel<<<dim3(1), dim3(1024), 0, stream>>>(cursor, rowptr, cursor, N);
    fill_csr_kernel<<<gE, blk, 0, stream>>>(src, dst, cursor, col, E);

    // ---- embed + lin -> A (embedding gather fused into X-load) ----
    gemm2<80, 96, 128, 96, 8, 6, false, false, true, false>
        <<<dim3(rowTiles), blk, 0, stream>>>(
        nullptr, nullptr, lin_W, nullptr, lin_b,
        x_layout, x_role, lemb, remb, nullptr, nullptr, A, N);

    // ---- layer 0: A -> C ----
    gather_mean_kernel<<<gGather, blk, 0, stream>>>(A, rowptr, col, B, N);
    gemm2<96, 96, 128, 96, 8, 6, true, true, false, false>
        <<<dim3(rowTiles), blk, 0, stream>>>(
        A, B, c0_rW, c0_lW, c0_lb, nullptr, nullptr, nullptr, nullptr,
        nullptr, nullptr, C, N);

    // ---- layer 1: C -> A ----
    gather_mean_kernel<<<gGather, blk, 0, stream>>>(C, rowptr, col, B, N);
    gemm2<96, 96, 128, 96, 8, 6, true, true, false, false>
        <<<dim3(rowTiles), blk, 0, stream>>>(
        C, B, c1_rW, c1_lW, c1_lb, nullptr, nullptr, nullptr, nullptr,
        nullptr, nullptr, A, N);

    // ---- layer 2: A -> C ----
    gather_mean_kernel<<<gGather, blk, 0, stream>>>(A, rowptr, col, B, N);
    gemm2<96, 96, 128, 96, 8, 6, true, true, false, false>
        <<<dim3(rowTiles), blk, 0, stream>>>(
        A, B, c2_rW, c2_lW, c2_lb, nullptr, nullptr, nullptr, nullptr,
        nullptr, nullptr, C, N);

    // ---- head: d0 (C -> H0), then d1+d2 fused (H0 -> out) ----
    gemm2<96, 256, 128, 128, 8, 8, true, false, false, false>
        <<<dim3(rowTiles * 2), blk, 0, stream>>>(
        C, nullptr, d0_W, nullptr, d0_b, nullptr, nullptr, nullptr, nullptr,
        nullptr, nullptr, H0, N);

    hipMemsetAsync(d_out, 0, (size_t)N * sizeof(float), stream);
    gemm2<256, 256, 128, 128, 8, 8, true, false, false, true>
        <<<dim3(rowTiles * 2), blk, 0, stream>>>(
        H0, nullptr, d1_W, nullptr, d1_b, nullptr, nullptr, nullptr, nullptr,
        d2_W, d2_b, (float*)d_out, N);
}

// Round 6
// 665.791 us; speedup vs baseline: 6.8992x; 1.0420x over previous
//
#include <hip/hip_runtime.h>
#include <cstddef>

// ---------------------------------------------------------------------------
// embed+concat -> Linear(80->96) -> 3x SAGEConv(96, mean) -> MLP(96->256->256->1)
// fp32. N = in_sizes[1], E = in_sizes[2]/2.
// Round 5: conflict-free col mapping (groups of 4/2), BM=64 for more waves,
//          BK=32 (half the barriers). Same fusion structure as round 3.
// ---------------------------------------------------------------------------

#define NB 256

// ---- CSR: count in-degree --------------------------------------------------
__global__ __launch_bounds__(NB) void count_int_kernel(const int* __restrict__ dst,
                                                       int* __restrict__ cnt, int E) {
    int e = blockIdx.x * NB + threadIdx.x;
    if (e < E) atomicAdd(&cnt[dst[e]], 1);
}

// ---- CSR: single-block exclusive scan --------------------------------------
__global__ __launch_bounds__(1024) void scan_kernel(const int* __restrict__ cnt,
                                                    int* __restrict__ rowptr,
                                                    int* __restrict__ cursor, int n) {
    __shared__ int buf[1024];
    __shared__ int carry;
    const int tid = threadIdx.x;
    if (tid == 0) carry = 0;
    __syncthreads();
    const int CH = 1024 * 8;
    for (int base = 0; base < n; base += CH) {
        int loc[8];
        int s = 0;
        #pragma unroll
        for (int q = 0; q < 8; ++q) {
            int i = base + tid * 8 + q;
            int v = (i < n) ? cnt[i] : 0;
            loc[q] = s;
            s += v;
        }
        buf[tid] = s;
        __syncthreads();
        for (int off = 1; off < 1024; off <<= 1) {
            int t = (tid >= off) ? buf[tid - off] : 0;
            __syncthreads();
            buf[tid] += t;
            __syncthreads();
        }
        int tpref = carry + buf[tid] - s;
        #pragma unroll
        for (int q = 0; q < 8; ++q) {
            int i = base + tid * 8 + q;
            if (i < n) {
                int v = tpref + loc[q];
                rowptr[i] = v;
                cursor[i] = v;
            }
        }
        int chunk = buf[1023];
        __syncthreads();
        if (tid == 0) carry += chunk;
        __syncthreads();
    }
    if (tid == 0) rowptr[n] = carry;
}

// ---- CSR: fill column (src) list -------------------------------------------
__global__ __launch_bounds__(NB) void fill_csr_kernel(const int* __restrict__ src,
                                                      const int* __restrict__ dst,
                                                      int* __restrict__ cursor,
                                                      int* __restrict__ col, int E) {
    int e = blockIdx.x * NB + threadIdx.x;
    if (e >= E) return;
    int p = atomicAdd(&cursor[dst[e]], 1);
    col[p] = src[e];
}

// ---- gather-mean: G[n] = mean_{j in col[rowptr[n]:rowptr[n+1]]} X[j] -------
__global__ __launch_bounds__(NB) void gather_mean_kernel(
    const float* __restrict__ X, const int* __restrict__ rowptr,
    const int* __restrict__ col, float* __restrict__ G, int N) {
    int idx = blockIdx.x * NB + threadIdx.x;
    int node = idx / 24;
    if (node >= N) return;
    int c = idx - node * 24;
    const int s = rowptr[node], pe = rowptr[node + 1];
    float4 acc = {0.f, 0.f, 0.f, 0.f};
    int p = s;
    for (; p + 3 < pe; p += 4) {
        int j0 = col[p], j1 = col[p + 1], j2 = col[p + 2], j3 = col[p + 3];
        float4 v0 = *reinterpret_cast<const float4*>(&X[(size_t)j0 * 96 + 4 * c]);
        float4 v1 = *reinterpret_cast<const float4*>(&X[(size_t)j1 * 96 + 4 * c]);
        float4 v2 = *reinterpret_cast<const float4*>(&X[(size_t)j2 * 96 + 4 * c]);
        float4 v3 = *reinterpret_cast<const float4*>(&X[(size_t)j3 * 96 + 4 * c]);
        acc.x += (v0.x + v1.x) + (v2.x + v3.x);
        acc.y += (v0.y + v1.y) + (v2.y + v3.y);
        acc.z += (v0.z + v1.z) + (v2.z + v3.z);
        acc.w += (v0.w + v1.w) + (v2.w + v3.w);
    }
    for (; p < pe; ++p) {
        int j = col[p];
        float4 v = *reinterpret_cast<const float4*>(&X[(size_t)j * 96 + 4 * c]);
        acc.x += v.x; acc.y += v.y; acc.z += v.z; acc.w += v.w;
    }
    int deg = pe - s;
    float inv = (deg > 0) ? 1.f / (float)deg : 0.f;
    acc.x *= inv; acc.y *= inv; acc.z *= inv; acc.w *= inv;
    *reinterpret_cast<float4*>(&G[(size_t)node * 96 + 4 * c]) = acc;
}

// ---- register-tiled GEMM ---------------------------------------------------
// Y = act(X @ Wx^T [+ G @ Wg^T] + bias); EMB: X-load gathers embeddings;
// FDOT: out[r] += relu(row).d2w (atomicAdd). Grid 1D, col-tile fastest.
// 256 thr as 16x16. Thread (tx,ty): rows ty*TM+i, cols tx*G4+(j%G4)+SPAN*(j/G4)
// (bank-conflict-free b-loads: lane stride G4*4 B).
template <int K, int OUT, int BM, int BN, int TM, int TN, int BK,
          bool RELU, bool SAGE, bool EMB, bool FDOT>
__global__ __launch_bounds__(NB) void gemm2(
    const float* __restrict__ X, const float* __restrict__ G,
    const float* __restrict__ Wx, const float* __restrict__ Wg,
    const float* __restrict__ bias,
    const int* __restrict__ xl, const int* __restrict__ xr,
    const float* __restrict__ lemb, const float* __restrict__ remb,
    const float* __restrict__ d2w, const float* __restrict__ d2b,
    float* __restrict__ Y, int nrows) {
    constexpr int G4   = (TN % 4 == 0) ? 4 : 2;   // col group size
    constexpr int SPAN = 16 * G4;                 // group stride
    constexpr int QX   = BK / 4;
    constexpr int CT   = OUT / BN;
    constexpr int KT   = SAGE ? 2 * K : K;
    __shared__ float Xs[BK][BM + 4];
    __shared__ float Ws[BK][BN + 4];

    const int t = threadIdx.x;
    const int tx = t & 15, ty = t >> 4;
    const int bid = blockIdx.x;
    const int rowBase = (bid / CT) * BM;
    const int colTile = bid % CT;
    const int colBase = colTile * BN;

    float acc[TM][TN];
#pragma unroll
    for (int i = 0; i < TM; ++i)
#pragma unroll
        for (int j = 0; j < TN; ++j) acc[i][j] = 0.f;

    for (int k0 = 0; k0 < KT; k0 += BK) {
        const bool isG = SAGE && (k0 >= K);
        const float* __restrict__ Xp = isG ? G : X;
        const float* __restrict__ Wp = isG ? Wg : Wx;
        const int kl = isG ? (k0 - K) : k0;

        // X tile -> Xs[k][m] (transposed)
        for (int v = t; v < BM * QX; v += NB) {
            int m = v / QX, q = v % QX;
            int r = rowBase + m;
            float4 f = {0.f, 0.f, 0.f, 0.f};
            if (r < nrows) {
                if (EMB) {
                    int kk = kl + 4 * q;
                    if (kk < 64) {
                        int l = kk >> 4, c = kk & 15;
                        f = *reinterpret_cast<const float4*>(
                            &lemb[(size_t)xl[r * 4 + l] * 16 + c]);
                    } else {
                        f = *reinterpret_cast<const float4*>(
                            &remb[(size_t)xr[r] * 16 + (kk - 64)]);
                    }
                } else {
                    f = *reinterpret_cast<const float4*>(&Xp[(size_t)r * K + kl + 4 * q]);
                }
            }
            Xs[4 * q + 0][m] = f.x;
            Xs[4 * q + 1][m] = f.y;
            Xs[4 * q + 2][m] = f.z;
            Xs[4 * q + 3][m] = f.w;
        }
        // W tile -> Ws[k][n] (transposed)
        for (int v = t; v < BN * QX; v += NB) {
            int n = v / QX, q = v % QX;
            float4 f = *reinterpret_cast<const float4*>(
                &Wp[(size_t)(colBase + n) * K + kl + 4 * q]);
            Ws[4 * q + 0][n] = f.x;
            Ws[4 * q + 1][n] = f.y;
            Ws[4 * q + 2][n] = f.z;
            Ws[4 * q + 3][n] = f.w;
        }
        __syncthreads();

#pragma unroll
        for (int k = 0; k < BK; ++k) {
            float a[TM], b[TN];
#pragma unroll
            for (int i = 0; i < TM; ++i) a[i] = Xs[k][ty * TM + i];
#pragma unroll
            for (int j = 0; j < TN; ++j)
                b[j] = Ws[k][tx * G4 + (j % G4) + SPAN * (j / G4)];
#pragma unroll
            for (int i = 0; i < TM; ++i)
#pragma unroll
                for (int j = 0; j < TN; ++j) acc[i][j] += a[i] * b[j];
        }
        __syncthreads();
    }

    if (!FDOT) {
#pragma unroll
        for (int i = 0; i < TM; ++i) {
            int r = rowBase + ty * TM + i;
            if (r >= nrows) continue;
#pragma unroll
            for (int g = 0; g < TN / G4; ++g) {
                int cb = colBase + tx * G4 + SPAN * g;
                float vv[G4];
#pragma unroll
                for (int u = 0; u < G4; ++u) {
                    float v = acc[i][g * G4 + u] + bias[cb + u];
                    if (RELU) v = fmaxf(v, 0.f);
                    vv[u] = v;
                }
                if (G4 == 4) {
                    float4 o = {vv[0], vv[1], vv[2], vv[3]};
                    *reinterpret_cast<float4*>(&Y[(size_t)r * OUT + cb]) = o;
                } else {
                    float2 o = {vv[0], vv[1]};
                    *reinterpret_cast<float2*>(&Y[(size_t)r * OUT + cb]) = o;
                }
            }
        }
    } else {
#pragma unroll
        for (int i = 0; i < TM; ++i) {
            int r = rowBase + ty * TM + i;
            float p = 0.f;
#pragma unroll
            for (int j = 0; j < TN; ++j) {
                int c = colBase + tx * G4 + (j % G4) + SPAN * (j / G4);
                float v = fmaxf(acc[i][j] + bias[c], 0.f);
                p += v * d2w[c];
            }
#pragma unroll
            for (int off = 1; off < 16; off <<= 1) p += __shfl_xor(p, off);
            if (tx == 0 && r < nrows)
                atomicAdd(&Y[r], p + (colTile == 0 ? d2b[0] : 0.f));
        }
    }
}

// ---------------------------------------------------------------------------
extern "C" void kernel_launch(void* const* d_in, const int* in_sizes, int n_in,
                              void* d_out, int out_size, void* d_ws, size_t ws_size,
                              hipStream_t stream) {
    const int*   x_layout = (const int*)d_in[0];
    const int*   x_role   = (const int*)d_in[1];
    const int*   ei       = (const int*)d_in[2];
    const float* lemb     = (const float*)d_in[3];
    const float* remb     = (const float*)d_in[4];
    const float* lin_W    = (const float*)d_in[5];
    const float* lin_b    = (const float*)d_in[6];
    const float* c0_lW    = (const float*)d_in[7];
    const float* c0_lb    = (const float*)d_in[8];
    const float* c0_rW    = (const float*)d_in[9];
    const float* c1_lW    = (const float*)d_in[10];
    const float* c1_lb    = (const float*)d_in[11];
    const float* c1_rW    = (const float*)d_in[12];
    const float* c2_lW    = (const float*)d_in[13];
    const float* c2_lb    = (const float*)d_in[14];
    const float* c2_rW    = (const float*)d_in[15];
    const float* d0_W     = (const float*)d_in[16];
    const float* d0_b     = (const float*)d_in[17];
    const float* d1_W     = (const float*)d_in[18];
    const float* d1_b     = (const float*)d_in[19];
    const float* d2_W     = (const float*)d_in[20];
    const float* d2_b     = (const float*)d_in[21];

    const int N = in_sizes[1];
    const int E = in_sizes[2] / 2;
    const int* src = ei;
    const int* dst = ei + E;

    // workspace (4-byte elems):
    //   R0 (256N): early = [rowptr(N+1)|cursor(N)|col(E)]; late = H0(256N)
    //   then A(96N) | B(96N) | C(96N)
    float* ws     = (float*)d_ws;
    float* H0     = ws;
    int*   rowptr = (int*)d_ws;
    int*   cursor = rowptr + (N + 1);
    int*   col    = cursor + N;
    float* A      = ws + (size_t)256 * N;
    float* B      = A + (size_t)96 * N;
    float* C      = B + (size_t)96 * N;

    const dim3 blk(NB);
    const int rt64  = (N + 63) / 64;    // BM=64 row tiles
    const int rt128 = (N + 127) / 128;  // BM=128 row tiles
    const dim3 gE((E + NB - 1) / NB);
    const dim3 gGather(((size_t)N * 24 + NB - 1) / NB);

    // ---- CSR build ----
    hipMemsetAsync(cursor, 0, (size_t)N * sizeof(int), stream);
    count_int_kernel<<<gE, blk, 0, stream>>>(dst, cursor, E);
    scan_kernel<<<dim3(1), dim3(1024), 0, stream>>>(cursor, rowptr, cursor, N);
    fill_csr_kernel<<<gE, blk, 0, stream>>>(src, dst, cursor, col, E);

    // ---- embed + lin -> A (embedding fused into X-load; K=80 needs BK=16) --
    gemm2<80, 96, 128, 96, 8, 6, 16, false, false, true, false>
        <<<dim3(rt128), blk, 0, stream>>>(
        nullptr, nullptr, lin_W, nullptr, lin_b,
        x_layout, x_role, lemb, remb, nullptr, nullptr, A, N);

    // ---- layer 0: A -> C ----
    gather_mean_kernel<<<gGather, blk, 0, stream>>>(A, rowptr, col, B, N);
    gemm2<96, 96, 64, 96, 4, 6, 32, true, true, false, false>
        <<<dim3(rt64), blk, 0, stream>>>(
        A, B, c0_rW, c0_lW, c0_lb, nullptr, nullptr, nullptr, nullptr,
        nullptr, nullptr, C, N);

    // ---- layer 1: C -> A ----
    gather_mean_kernel<<<gGather, blk, 0, stream>>>(C, rowptr, col, B, N);
    gemm2<96, 96, 64, 96, 4, 6, 32, true, true, false, false>
        <<<dim3(rt64), blk, 0, stream>>>(
        C, B, c1_rW, c1_lW, c1_lb, nullptr, nullptr, nullptr, nullptr,
        nullptr, nullptr, A, N);

    // ---- layer 2: A -> C ----
    gather_mean_kernel<<<gGather, blk, 0, stream>>>(A, rowptr, col, B, N);
    gemm2<96, 96, 64, 96, 4, 6, 32, true, true, false, false>
        <<<dim3(rt64), blk, 0, stream>>>(
        A, B, c2_rW, c2_lW, c2_lb, nullptr, nullptr, nullptr, nullptr,
        nullptr, nullptr, C, N);

    // ---- head: d0 (C -> H0), then d1+d2 fused (H0 -> out) ----
    gemm2<96, 256, 64, 128, 4, 8, 32, true, false, false, false>
        <<<dim3(rt64 * 2), blk, 0, stream>>>(
        C, nullptr, d0_W, nullptr, d0_b, nullptr, nullptr, nullptr, nullptr,
        nullptr, nullptr, H0, N);

    hipMemsetAsync(d_out, 0, (size_t)N * sizeof(float), stream);
    gemm2<256, 256, 64, 128, 4, 8, 32, true, false, false, true>
        <<<dim3(rt64 * 2), blk, 0, stream>>>(
        H0, nullptr, d1_W, nullptr, d1_b, nullptr, nullptr, nullptr, nullptr,
        d2_W, d2_b, (float*)d_out, N);
}